// Round 3
// baseline (4895.923 us; speedup 1.0000x reference)
//
#include <hip/hip_runtime.h>
#include <hip/hip_bf16.h>

typedef __attribute__((ext_vector_type(8))) __bf16 bf16x8;
typedef __attribute__((ext_vector_type(16))) float f32x16;

#define NB 256     // batch
#define HD 1024    // hidden
#define G3 3072    // 3*H
#define NT 128     // time steps

// ---------------- workspace layout (bytes) ----------------
static const size_t OFF_WHH  = 0;                                   // [d][3072][1024] bf16 (k bit2<->3 swapped)
static const size_t OFF_WIH  = OFF_WHH + (size_t)2*G3*HD*2;         // [d][3072][1024] bf16 (k-swapped)
static const size_t OFF_X16  = OFF_WIH + (size_t)2*G3*HD*2;         // [256][1024] bf16 (k-swapped)
static const size_t OFF_GI   = OFF_X16 + (size_t)NB*HD*2;           // [d][256][3072] f32 (natural)
static const size_t OFF_H32  = OFF_GI  + (size_t)2*NB*G3*4;         // [p][d][256][1024] f32 (natural)
static const size_t OFF_H16  = OFF_H32 + (size_t)4*NB*HD*4;         // [p][d][256][1024] bf16 (k-swapped)
static const size_t OFF_PART = OFF_H16 + (size_t)4*NB*HD*2;         // [b][t][64] f32
// total ~44.5 MiB

// swap bits 2 and 3 of a k-index (identical bijection applied to BOTH MFMA
// operand layouts -> provably output-invariant; kept from round 2).
__device__ inline int sw23(int k){ return (k & ~12) | ((k&4)<<1) | ((k&8)>>1); }

// ---------------- prep: cast to bf16 (k-swapped), zero h parity 0 ----------------
__global__ __launch_bounds__(256) void prep_kernel(
    const float* __restrict__ x,    const float* __restrict__ wihf,
    const float* __restrict__ whhf, const float* __restrict__ wihb,
    const float* __restrict__ whhb, char* __restrict__ ws)
{
  size_t i = (size_t)blockIdx.x*256 + threadIdx.x;   // grid covers 3145728
  __hip_bfloat16* whh = (__hip_bfloat16*)(ws+OFF_WHH);
  __hip_bfloat16* wih = (__hip_bfloat16*)(ws+OFF_WIH);
  __hip_bfloat16* x16 = (__hip_bfloat16*)(ws+OFF_X16);
  float*          h32 = (float*)(ws+OFF_H32);
  __hip_bfloat16* h16 = (__hip_bfloat16*)(ws+OFF_H16);
  int k = (int)(i & 1023);
  size_t ip = (i & ~(size_t)1023) | (size_t)sw23(k);
  if (i < (size_t)G3*HD) {
    whh[ip]                 = __float2bfloat16(whhf[i]);
    whh[(size_t)G3*HD + ip] = __float2bfloat16(whhb[i]);
    wih[ip]                 = __float2bfloat16(wihf[i]);
    wih[(size_t)G3*HD + ip] = __float2bfloat16(wihb[i]);
  }
  if (i < (size_t)NB*HD)   x16[ip] = __float2bfloat16(x[i]);
  if (i < (size_t)2*NB*HD) { h32[i] = 0.f; h16[i] = __float2bfloat16(0.f); }
}

// ---------------- fused GEMM (+gates for steps) ----------------
// Grid: 256 blocks = (dir 2) x (rowtile 4: 64 rows) x (coltile 32: 32 hcols)
// Block: 128 threads = 2 waves; wave w owns rows [w*32, w*32+31], all 96 gh cols.
// Reg-staged float4 global->LDS, coalesced (8 lanes x 16B = 128B per row),
// XOR slot swizzle so ds_write_b128 and ds_read_b128 are both conflict-free.
// No inline asm: compiler owns all waitcnts.
template<int INIT>
__global__ __launch_bounds__(128,1)
void gru_gemm(char* __restrict__ ws,
              const float* __restrict__ bihf, const float* __restrict__ bihb,
              const float* __restrict__ bhhf, const float* __restrict__ bhhb,
              const float* __restrict__ wout, int t)
{
  const int bid = blockIdx.x;
  const int ct = bid & 31, rt = (bid>>5)&3, d = bid>>7;
  const int tid = threadIdx.x;
  const int w = tid>>6, lane = tid&63;
  const int jl = lane&31;
  const int j0 = ct*32, r0 = rt*64;
  const int p = t & 1;

  const __hip_bfloat16* Wb = (const __hip_bfloat16*)(ws + (INIT?OFF_WIH:OFF_WHH))
                             + (size_t)d*G3*HD;
  const __hip_bfloat16* Ab = INIT
      ? (const __hip_bfloat16*)(ws+OFF_X16)
      : (const __hip_bfloat16*)(ws+OFF_H16) + (size_t)(p*2+d)*NB*HD;

  __shared__ __align__(16) __hip_bfloat16 Al[2][4096];   // 64 rows x 8 kc x 8 el, 8KB/buf
  __shared__ __align__(16) __hip_bfloat16 Bl[2][6144];   // 96 cols x 8 kc x 8 el, 12KB/buf

  f32x16 acc0, acc1, acc2;
  #pragma unroll
  for (int i=0;i<16;++i) { acc0[i]=0.f; acc1[i]=0.f; acc2[i]=0.f; }

  float4 gA[4], gB[6];
  auto load_regs = [&](int s){
    const int k0 = s*64;
    #pragma unroll
    for (int i=0;i<4;++i){ int c=tid+128*i; int row=c>>3, kc=c&7;
      gA[i] = *(const float4*)(Ab + (size_t)(r0+row)*HD + k0 + kc*8); }
    #pragma unroll
    for (int i=0;i<6;++i){ int c=tid+128*i; int col=c>>3, kc=c&7; int g=col>>5, jj=col&31;
      gB[i] = *(const float4*)(Wb + (size_t)(g*1024 + j0 + jj)*HD + k0 + kc*8); }
  };
  auto write_lds = [&](int buf){
    #pragma unroll
    for (int i=0;i<4;++i){ int c=tid+128*i; int ch = c ^ ((c>>3)&7);
      *(float4*)&Al[buf][ch*8] = gA[i]; }
    #pragma unroll
    for (int i=0;i<6;++i){ int c=tid+128*i; int ch = c ^ ((c>>3)&7);
      *(float4*)&Bl[buf][ch*8] = gB[i]; }
  };

  load_regs(0);
  write_lds(0);
  load_regs(1);

  const int arow = w*32 + jl;
  const int kh = lane>>5;
  for (int s=0;s<16;++s) {
    const int buf = s&1;
    __syncthreads();
    #pragma unroll
    for (int ks=0;ks<4;++ks) {
      const int kc = ks*2 + kh;
      bf16x8 a  = *(const bf16x8*)&Al[buf][(arow*8    + (kc^(arow&7)))*8];
      bf16x8 b0 = *(const bf16x8*)&Bl[buf][( jl*8     + (kc^(jl&7)))*8];
      bf16x8 b1 = *(const bf16x8*)&Bl[buf][((32+jl)*8 + (kc^(jl&7)))*8];
      bf16x8 b2 = *(const bf16x8*)&Bl[buf][((64+jl)*8 + (kc^(jl&7)))*8];
      acc0 = __builtin_amdgcn_mfma_f32_32x32x16_bf16(a, b0, acc0, 0,0,0);
      acc1 = __builtin_amdgcn_mfma_f32_32x32x16_bf16(a, b1, acc1, 0,0,0);
      acc2 = __builtin_amdgcn_mfma_f32_32x32x16_bf16(a, b2, acc2, 0,0,0);
    }
    if (s<15) { write_lds(buf^1); if (s<14) load_regs(s+2); }
  }

  const int j = j0 + jl;

  if (INIT) {
    float* gi = (float*)(ws+OFF_GI) + (size_t)d*NB*G3;
    const float* bih = d ? bihb : bihf;
    const float br = bih[j], bz = bih[1024+j], bn = bih[2048+j];
    #pragma unroll
    for (int q=0;q<16;++q) {
      int brow = (q&3) + 8*(q>>2) + 4*(lane>>5);
      int b = r0 + w*32 + brow;
      gi[(size_t)b*G3 +        j] = acc0[q] + br;
      gi[(size_t)b*G3 + 1024 + j] = acc1[q] + bz;
      gi[(size_t)b*G3 + 2048 + j] = acc2[q] + bn;
    }
  } else {
    const float* gi  = (const float*)(ws+OFF_GI) + (size_t)d*NB*G3;
    const float* bhh = d ? bhhb : bhhf;
    const float* h32p = (const float*)(ws+OFF_H32) + (size_t)(p*2+d)*NB*HD;
    float*          h32n = (float*)(ws+OFF_H32) + (size_t)((p^1)*2+d)*NB*HD;
    __hip_bfloat16* h16n = (__hip_bfloat16*)(ws+OFF_H16) + (size_t)((p^1)*2+d)*NB*HD;
    float* part = (float*)(ws+OFF_PART);
    const float br = bhh[j], bz = bhh[1024+j], bn = bhh[2048+j];
    const float wo = wout[d*HD + j];
    const int jsw = j0 + sw23(jl);          // k-swapped column for h16 store
    #pragma unroll
    for (int q=0;q<16;++q) {
      int brow = (q&3) + 8*(q>>2) + 4*(lane>>5);
      int b = r0 + w*32 + brow;
      float gir = gi[(size_t)b*G3 +        j];
      float giz = gi[(size_t)b*G3 + 1024 + j];
      float gin = gi[(size_t)b*G3 + 2048 + j];
      float rr  = 1.f/(1.f + __expf(-(gir + acc0[q] + br)));
      float zz  = 1.f/(1.f + __expf(-(giz + acc1[q] + bz)));
      float ghn = acc2[q] + bn;
      float ng  = tanhf(gin + rr*ghn);
      float hold = h32p[(size_t)b*HD + j];
      float hn = (1.f - zz)*ng + zz*hold;
      h32n[(size_t)b*HD + j]   = hn;
      h16n[(size_t)b*HD + jsw] = __float2bfloat16(hn);
      float pp = hn * wo;                      // partial of out[b,t]
      #pragma unroll
      for (int m=1;m<32;m<<=1) pp += __shfl_xor(pp, m, 64);
      if (jl==0) part[((size_t)b*NT + t)*64 + d*32 + ct] = pp;
    }
  }
}

// ---------------- finalize: one wave per (b,t) output, f32 OUTPUT ----------------
__global__ __launch_bounds__(256) void finalize_kernel(
    const char* __restrict__ ws, const float* __restrict__ bout,
    float* __restrict__ out)
{
  int widx = blockIdx.x*4 + (threadIdx.x>>6);   // output index b*128+t, 32768 total
  int lane = threadIdx.x & 63;
  const float* part = (const float*)(ws+OFF_PART);
  float v = part[(size_t)widx*64 + lane];
  #pragma unroll
  for (int m=1;m<64;m<<=1) v += __shfl_xor(v, m, 64);
  if (lane==0) out[widx] = v + bout[0];         // f32 — reference output dtype
}

// ---------------- launch ----------------
extern "C" void kernel_launch(void* const* d_in, const int* in_sizes, int n_in,
                              void* d_out, int out_size, void* d_ws, size_t ws_size,
                              hipStream_t stream)
{
  const float* x    = (const float*)d_in[0];
  // d_in[1] = n (always 128 for this problem)
  const float* wihf = (const float*)d_in[2];
  const float* whhf = (const float*)d_in[3];
  const float* bihf = (const float*)d_in[4];
  const float* bhhf = (const float*)d_in[5];
  const float* wihb = (const float*)d_in[6];
  const float* whhb = (const float*)d_in[7];
  const float* bihb = (const float*)d_in[8];
  const float* bhhb = (const float*)d_in[9];
  const float* wout = (const float*)d_in[10];
  const float* bout = (const float*)d_in[11];
  char* ws = (char*)d_ws;
  float* out = (float*)d_out;

  prep_kernel<<<12288, 256, 0, stream>>>(x, wihf, whhf, wihb, whhb, ws);
  gru_gemm<1><<<256, 128, 0, stream>>>(ws, bihf, bihb, bhhf, bhhb, wout, 0);
  for (int t=0; t<NT; ++t)
    gru_gemm<0><<<256, 128, 0, stream>>>(ws, bihf, bihb, bhhf, bhhb, wout, t);
  finalize_kernel<<<8192, 256, 0, stream>>>(ws, bout, out);
}

// Round 4
// 2853.790 us; speedup vs baseline: 1.7156x; 1.7156x over previous
//
#include <hip/hip_runtime.h>
#include <hip/hip_bf16.h>

typedef __attribute__((ext_vector_type(8))) __bf16 bf16x8;
typedef __attribute__((ext_vector_type(16))) float f32x16;

#define NB 256     // batch
#define HD 1024    // hidden
#define G3 3072    // 3*H
#define NT 128     // time steps

// ---------------- workspace layout (bytes) ----------------
static const size_t OFF_WHH  = 0;                                   // [d][3072][1024] bf16
static const size_t OFF_WIH  = OFF_WHH + (size_t)2*G3*HD*2;         // [d][3072][1024] bf16
static const size_t OFF_X16  = OFF_WIH + (size_t)2*G3*HD*2;         // [256][1024] bf16
static const size_t OFF_GI   = OFF_X16 + (size_t)NB*HD*2;           // gi_perm: [bid][r][48][lane64] f32
static const size_t OFF_H32  = OFF_GI  + (size_t)2*NB*G3*4;         // h32_perm: [p][bid][r][16][lane64] f32
static const size_t OFF_H16  = OFF_H32 + (size_t)4*NB*HD*4;         // [p][d][256][1024] bf16 natural
static const size_t OFF_PART = OFF_H16 + (size_t)4*NB*HD*2;         // [b][t][64] f32

// ---------------- prep: cast to bf16, zero h (parity 0) ----------------
__global__ __launch_bounds__(256) void prep_kernel(
    const float* __restrict__ x,    const float* __restrict__ wihf,
    const float* __restrict__ whhf, const float* __restrict__ wihb,
    const float* __restrict__ whhb, char* __restrict__ ws)
{
  size_t i = (size_t)blockIdx.x*256 + threadIdx.x;   // grid covers 3145728
  __hip_bfloat16* whh = (__hip_bfloat16*)(ws+OFF_WHH);
  __hip_bfloat16* wih = (__hip_bfloat16*)(ws+OFF_WIH);
  __hip_bfloat16* x16 = (__hip_bfloat16*)(ws+OFF_X16);
  float*          h32 = (float*)(ws+OFF_H32);
  __hip_bfloat16* h16 = (__hip_bfloat16*)(ws+OFF_H16);
  if (i < (size_t)G3*HD) {
    whh[i]                 = __float2bfloat16(whhf[i]);
    whh[(size_t)G3*HD + i] = __float2bfloat16(whhb[i]);
    wih[i]                 = __float2bfloat16(wihf[i]);
    wih[(size_t)G3*HD + i] = __float2bfloat16(wihb[i]);
  }
  if (i < (size_t)NB*HD)   x16[i] = __float2bfloat16(x[i]);
  if (i < (size_t)2*NB*HD) { h32[i] = 0.f; h16[i] = __float2bfloat16(0.f); }
}

// ---------------- async global->LDS helper ----------------
__device__ inline void gl_lds16(const void* g, void* l) {
  __builtin_amdgcn_global_load_lds(
      (const __attribute__((address_space(1))) void*)g,
      (__attribute__((address_space(3))) void*)l, 16, 0, 0);
}

// ---------------- fused GEMM (+gates for steps) ----------------
// Grid: 256 blocks = (dir 2) x (rowtile 4: 64 rows) x (coltile 32: 32 hcols);
//       bid = d*128 + rt*32 + ct  (ct = bid&31 pins each weight tile to one XCD).
// Block: 256 threads = 4 waves = (rowhalf r: 32 rows) x (K-slice q: 512 of K).
// K loop: 8 phases of 64; global_load_lds staging, pre-swizzled global source
// + swizzled ds_read (both-sides swizzle, conflict-free); 1 barrier/phase,
// phase s+1 staged at top of phase s (drain at barrier is ~free: 1 phase > L2 lat).
// End: K-slice partial accumulators reduced through LDS; epilogue on q==0 waves.
template<int INIT>
__global__ __launch_bounds__(256,1)
void gru_gemm(char* __restrict__ ws,
              const float* __restrict__ bihf, const float* __restrict__ bihb,
              const float* __restrict__ bhhf, const float* __restrict__ bhhb,
              const float* __restrict__ wout, int t)
{
  const int bid = blockIdx.x;
  const int ct = bid & 31, rt = (bid>>5)&3, d = bid>>7;
  const int tid = threadIdx.x;
  const int w = tid>>6, lane = tid&63;
  const int jl = lane&31;
  const int r = w&1, q = w>>1;       // rowhalf, K-slice
  const int j0 = ct*32, r0 = rt*64;
  const int p = t & 1;

  const __hip_bfloat16* Wb = (const __hip_bfloat16*)(ws + (INIT?OFF_WIH:OFF_WHH))
                             + (size_t)d*G3*HD;
  const __hip_bfloat16* Ab = INIT
      ? (const __hip_bfloat16*)(ws+OFF_X16)
      : (const __hip_bfloat16*)(ws+OFF_H16) + (size_t)(p*2+d)*NB*HD;

  // A: [buf2][q2][slot512][8]  = 32 KB ; B: [buf2][q2][slot768][8] = 48 KB
  __shared__ __align__(16) __hip_bfloat16 smem[40960];
  #define ABASE(buf,qq) (((buf)*2+(qq))*512*8)
  #define BBASE(buf,qq) (16384 + ((buf)*2+(qq))*768*8)

  f32x16 acc0, acc1, acc2;
  #pragma unroll
  for (int i=0;i<16;++i) { acc0[i]=0.f; acc1[i]=0.f; acc2[i]=0.f; }

  // stage phase s_ into buf = s_&1. Per thread: 4 A + 6 B global_load_lds.
  // Global source pre-swizzled (kcl = (slot&7)^(row&7)) so linear LDS dest
  // ends up XOR-swizzled == what the ds_read side expects.
  auto stage = [&](int s_){
    const int buf = s_&1;
    #pragma unroll
    for (int qq=0;qq<2;++qq){
      const int k0 = qq*512 + s_*64;
      #pragma unroll
      for (int i=0;i<2;++i){
        int slot = i*256 + tid; int row = slot>>3; int kcl = (slot&7)^(row&7);
        gl_lds16(Ab + (size_t)(r0+row)*HD + k0 + kcl*8,
                 &smem[ABASE(buf,qq) + slot*8]);
      }
      #pragma unroll
      for (int i=0;i<3;++i){
        int slot = i*256 + tid; int col = slot>>3; int kcl = (slot&7)^(col&7);
        int g = col>>5, jj = col&31;
        gl_lds16(Wb + (size_t)(g*1024 + j0 + jj)*HD + k0 + kcl*8,
                 &smem[BBASE(buf,qq) + slot*8]);
      }
    }
  };

  stage(0); stage(1);
  __syncthreads();

  const int arow = r*32 + jl;
  const int kh = lane>>5;
  for (int s=0;s<8;++s) {
    const int buf = s&1;
    if (s>0 && s<7) stage(s+1);   // writes buf[(s+1)&1]=buf[(s-1)&1]: safe post-barrier
    #pragma unroll
    for (int ks=0;ks<4;++ks) {
      const int kc = ks*2 + kh;
      bf16x8 a  = *(const bf16x8*)&smem[ABASE(buf,q) + (arow*8    + (kc^(arow&7)))*8];
      bf16x8 b0 = *(const bf16x8*)&smem[BBASE(buf,q) + ( jl*8     + (kc^(jl&7)))*8];
      bf16x8 b1 = *(const bf16x8*)&smem[BBASE(buf,q) + ((32+jl)*8 + (kc^(jl&7)))*8];
      bf16x8 b2 = *(const bf16x8*)&smem[BBASE(buf,q) + ((64+jl)*8 + (kc^(jl&7)))*8];
      acc0 = __builtin_amdgcn_mfma_f32_32x32x16_bf16(a, b0, acc0, 0,0,0);
      acc1 = __builtin_amdgcn_mfma_f32_32x32x16_bf16(a, b1, acc1, 0,0,0);
      acc2 = __builtin_amdgcn_mfma_f32_32x32x16_bf16(a, b2, acc2, 0,0,0);
    }
    __syncthreads();   // all reads of buf done; also drains stage(s+1) loads (issued 1 phase ago)
  }

  // ---- cross-K-slice reduction through LDS (aliases staging buffers) ----
  float* red = (float*)smem;                     // [r2][lane64][48]
  if (q==1) {
    const int base = (r*64+lane)*48;
    #pragma unroll
    for (int e=0;e<16;++e){ red[base+e]=acc0[e]; red[base+16+e]=acc1[e]; red[base+32+e]=acc2[e]; }
  }
  __syncthreads();
  if (q==1) return;
  {
    const int base = (r*64+lane)*48;
    #pragma unroll
    for (int e=0;e<16;++e){ acc0[e]+=red[base+e]; acc1[e]+=red[base+16+e]; acc2[e]+=red[base+32+e]; }
  }

  const int j = j0 + jl;
  const size_t TI = (size_t)(bid*2 + r);        // thread-row base for permuted buffers

  if (INIT) {
    float* gi = (float*)(ws+OFF_GI);
    const float* bih = d ? bihb : bihf;
    const float br = bih[j], bz = bih[1024+j], bn = bih[2048+j];
    #pragma unroll
    for (int qq=0;qq<16;++qq) {
      gi[(TI*48 + qq*3+0)*64 + lane] = acc0[qq] + br;
      gi[(TI*48 + qq*3+1)*64 + lane] = acc1[qq] + bz;
      gi[(TI*48 + qq*3+2)*64 + lane] = acc2[qq] + bn;
    }
  } else {
    const float* gi  = (const float*)(ws+OFF_GI);
    const float* bhh = d ? bhhb : bhhf;
    const float* h32p = (const float*)(ws+OFF_H32) + (size_t)p*524288;
    float*          h32n = (float*)(ws+OFF_H32) + (size_t)(p^1)*524288;
    __hip_bfloat16* h16n = (__hip_bfloat16*)(ws+OFF_H16) + (size_t)((p^1)*2+d)*NB*HD;
    float* part = (float*)(ws+OFF_PART);
    const float br = bhh[j], bz = bhh[1024+j], bn = bhh[2048+j];
    const float wo = wout[d*HD + j];
    #pragma unroll
    for (int qq=0;qq<16;++qq) {
      int brow = (qq&3) + 8*(qq>>2) + 4*(lane>>5);
      int b = r0 + r*32 + brow;
      float gir = gi[(TI*48 + qq*3+0)*64 + lane];
      float giz = gi[(TI*48 + qq*3+1)*64 + lane];
      float gin = gi[(TI*48 + qq*3+2)*64 + lane];
      float rr  = 1.f/(1.f + __expf(-(gir + acc0[qq] + br)));
      float zz  = 1.f/(1.f + __expf(-(giz + acc1[qq] + bz)));
      float ghn = acc2[qq] + bn;
      float ng  = tanhf(gin + rr*ghn);
      float hold = h32p[(TI*16 + qq)*64 + lane];
      float hn = (1.f - zz)*ng + zz*hold;
      h32n[(TI*16 + qq)*64 + lane] = hn;
      h16n[(size_t)b*HD + j] = __float2bfloat16(hn);
      float pp = hn * wo;                      // partial of out[b,t]
      #pragma unroll
      for (int m=1;m<32;m<<=1) pp += __shfl_xor(pp, m, 64);
      if (jl==0) part[((size_t)b*NT + t)*64 + d*32 + ct] = pp;
    }
  }
  #undef ABASE
  #undef BBASE
}

// ---------------- finalize: one wave per (b,t) output, f32 OUTPUT ----------------
__global__ __launch_bounds__(256) void finalize_kernel(
    const char* __restrict__ ws, const float* __restrict__ bout,
    float* __restrict__ out)
{
  int widx = blockIdx.x*4 + (threadIdx.x>>6);   // output index b*128+t, 32768 total
  int lane = threadIdx.x & 63;
  const float* part = (const float*)(ws+OFF_PART);
  float v = part[(size_t)widx*64 + lane];
  #pragma unroll
  for (int m=1;m<64;m<<=1) v += __shfl_xor(v, m, 64);
  if (lane==0) out[widx] = v + bout[0];
}

// ---------------- launch ----------------
extern "C" void kernel_launch(void* const* d_in, const int* in_sizes, int n_in,
                              void* d_out, int out_size, void* d_ws, size_t ws_size,
                              hipStream_t stream)
{
  const float* x    = (const float*)d_in[0];
  // d_in[1] = n (always 128 for this problem)
  const float* wihf = (const float*)d_in[2];
  const float* whhf = (const float*)d_in[3];
  const float* bihf = (const float*)d_in[4];
  const float* bhhf = (const float*)d_in[5];
  const float* wihb = (const float*)d_in[6];
  const float* whhb = (const float*)d_in[7];
  const float* bihb = (const float*)d_in[8];
  const float* bhhb = (const float*)d_in[9];
  const float* wout = (const float*)d_in[10];
  const float* bout = (const float*)d_in[11];
  char* ws = (char*)d_ws;
  float* out = (float*)d_out;

  prep_kernel<<<12288, 256, 0, stream>>>(x, wihf, whhf, wihb, whhb, ws);
  gru_gemm<1><<<256, 256, 0, stream>>>(ws, bihf, bihb, bhhf, bhhb, wout, 0);
  for (int t=0; t<NT; ++t)
    gru_gemm<0><<<256, 256, 0, stream>>>(ws, bihf, bihb, bhhf, bhhb, wout, t);
  finalize_kernel<<<8192, 256, 0, stream>>>(ws, bout, out);
}

// Round 5
// 2742.859 us; speedup vs baseline: 1.7850x; 1.0404x over previous
//
#include <hip/hip_runtime.h>
#include <hip/hip_bf16.h>

typedef __attribute__((ext_vector_type(8))) __bf16 bf16x8;
typedef __attribute__((ext_vector_type(16))) float f32x16;

#define NB 256     // batch
#define HD 1024    // hidden
#define G3 3072    // 3*H
#define NT 128     // time steps

// ---------------- workspace layout (bytes) ----------------
static const size_t OFF_WHH  = 0;                                   // [d][3072][1024] bf16
static const size_t OFF_WIH  = OFF_WHH + (size_t)2*G3*HD*2;         // [d][3072][1024] bf16
static const size_t OFF_X16  = OFF_WIH + (size_t)2*G3*HD*2;         // [256][1024] bf16
static const size_t OFF_GI   = OFF_X16 + (size_t)NB*HD*2;           // gi_perm: [bid][r][48][lane64] f32
static const size_t OFF_H32  = OFF_GI  + (size_t)2*NB*G3*4;         // h32_perm: [p][bid][r][16][lane64] f32
static const size_t OFF_H16  = OFF_H32 + (size_t)4*NB*HD*4;         // [p][d][256][1024] bf16 natural
static const size_t OFF_PART = OFF_H16 + (size_t)4*NB*HD*2;         // [b][t][64] f32

// ---------------- prep: cast to bf16, zero h (parity 0) ----------------
__global__ __launch_bounds__(256) void prep_kernel(
    const float* __restrict__ x,    const float* __restrict__ wihf,
    const float* __restrict__ whhf, const float* __restrict__ wihb,
    const float* __restrict__ whhb, char* __restrict__ ws)
{
  size_t i = (size_t)blockIdx.x*256 + threadIdx.x;   // grid covers 3145728
  __hip_bfloat16* whh = (__hip_bfloat16*)(ws+OFF_WHH);
  __hip_bfloat16* wih = (__hip_bfloat16*)(ws+OFF_WIH);
  __hip_bfloat16* x16 = (__hip_bfloat16*)(ws+OFF_X16);
  float*          h32 = (float*)(ws+OFF_H32);
  __hip_bfloat16* h16 = (__hip_bfloat16*)(ws+OFF_H16);
  if (i < (size_t)G3*HD) {
    whh[i]                 = __float2bfloat16(whhf[i]);
    whh[(size_t)G3*HD + i] = __float2bfloat16(whhb[i]);
    wih[i]                 = __float2bfloat16(wihf[i]);
    wih[(size_t)G3*HD + i] = __float2bfloat16(wihb[i]);
  }
  if (i < (size_t)NB*HD)   x16[i] = __float2bfloat16(x[i]);
  if (i < (size_t)2*NB*HD) { h32[i] = 0.f; h16[i] = __float2bfloat16(0.f); }
}

// ---------------- async global->LDS helper ----------------
__device__ inline void gl_lds16(const void* g, void* l) {
  __builtin_amdgcn_global_load_lds(
      (const __attribute__((address_space(1))) void*)g,
      (__attribute__((address_space(3))) void*)l, 16, 0, 0);
}

// ---------------- fused GEMM (+gates for steps) ----------------
// Grid: 256 blocks = (dir 2) x (rowtile 4: 64 rows) x (coltile 32: 32 hcols);
//       bid = d*128 + rt*32 + ct  (blocks sharing a weight tile land on one XCD).
// Block: 256 threads = 4 waves = (rowhalf r: 32 rows) x (K-slice q: 512 of K).
// K loop: 8 phases of 64, 3-buffer staging pipeline with COUNTED vmcnt (T3+T4):
// prologue stages 0,1,2; phase s waits vmcnt(20) (own stage-s loads done, two
// stages stay in flight -> HBM latency hidden by ~2 phases), raw s_barrier,
// MFMA on buf s%3, reads-done barrier, stage(s+3) refills buf s%3.
template<int INIT>
__global__ __launch_bounds__(256,1)
void gru_gemm(char* __restrict__ ws,
              const float* __restrict__ bihf, const float* __restrict__ bihb,
              const float* __restrict__ bhhf, const float* __restrict__ bhhb,
              const float* __restrict__ wout, int t)
{
  const int bid = blockIdx.x;
  const int ct = bid & 31, rt = (bid>>5)&3, d = bid>>7;
  const int tid = threadIdx.x;
  const int w = tid>>6, lane = tid&63;
  const int jl = lane&31;
  const int r = w&1, q = w>>1;       // rowhalf, K-slice
  const int j0 = ct*32, r0 = rt*64;
  const int p = t & 1;

  const __hip_bfloat16* Wb = (const __hip_bfloat16*)(ws + (INIT?OFF_WIH:OFF_WHH))
                             + (size_t)d*G3*HD;
  const __hip_bfloat16* Ab = INIT
      ? (const __hip_bfloat16*)(ws+OFF_X16)
      : (const __hip_bfloat16*)(ws+OFF_H16) + (size_t)(p*2+d)*NB*HD;

  // 3 buffers: A [3][q2][512 slots][8el] = 48 KB ; B [3][q2][768][8] = 72 KB
  __shared__ __align__(16) __hip_bfloat16 smem[61440];
  #define ABASE(buf,qq) ((((buf)*2)+(qq))*4096)
  #define BBASE(buf,qq) (24576 + (((buf)*2)+(qq))*6144)

  f32x16 acc0, acc1, acc2;
  #pragma unroll
  for (int i=0;i<16;++i) { acc0[i]=0.f; acc1[i]=0.f; acc2[i]=0.f; }

  // stage phase s_ into buf = s_%3. Per thread: 4 A + 6 B global_load_lds
  // (10 vmcnt units). Global source pre-swizzled so linear LDS dest ends up
  // XOR-swizzled to match the ds_read side (conflict-free both sides).
  auto stage = [&](int s_){
    const int buf = s_%3;
    #pragma unroll
    for (int qq=0;qq<2;++qq){
      const int k0 = qq*512 + s_*64;
      #pragma unroll
      for (int i=0;i<2;++i){
        int slot = i*256 + tid; int row = slot>>3; int kcl = (slot&7)^(row&7);
        gl_lds16(Ab + (size_t)(r0+row)*HD + k0 + kcl*8,
                 &smem[ABASE(buf,qq) + slot*8]);
      }
      #pragma unroll
      for (int i=0;i<3;++i){
        int slot = i*256 + tid; int col = slot>>3; int kcl = (slot&7)^(col&7);
        int g = col>>5, jj = col&31;
        gl_lds16(Wb + (size_t)(g*1024 + j0 + jj)*HD + k0 + kcl*8,
                 &smem[BBASE(buf,qq) + slot*8]);
      }
    }
  };

  stage(0); stage(1); stage(2);       // 30 loads in flight per wave

  const int arow = r*32 + jl;
  const int kh = lane>>5;
  for (int s=0;s<8;++s) {
    const int buf = s%3;
    // wait own stage(s) complete; keep later stages in flight (never drain mid-loop)
    if      (s<6)  asm volatile("s_waitcnt vmcnt(20)" ::: "memory");
    else if (s==6) asm volatile("s_waitcnt vmcnt(10)" ::: "memory");
    else           asm volatile("s_waitcnt vmcnt(0)"  ::: "memory");
    __builtin_amdgcn_s_barrier();          // all waves' stage(s) done -> buf ready
    __builtin_amdgcn_sched_barrier(0);
    #pragma unroll
    for (int ks=0;ks<4;++ks) {
      const int kc = ks*2 + kh;
      bf16x8 a  = *(const bf16x8*)&smem[ABASE(buf,q) + (arow*8    + (kc^(arow&7)))*8];
      bf16x8 b0 = *(const bf16x8*)&smem[BBASE(buf,q) + ( jl*8     + (kc^(jl&7)))*8];
      bf16x8 b1 = *(const bf16x8*)&smem[BBASE(buf,q) + ((32+jl)*8 + (kc^(jl&7)))*8];
      bf16x8 b2 = *(const bf16x8*)&smem[BBASE(buf,q) + ((64+jl)*8 + (kc^(jl&7)))*8];
      acc0 = __builtin_amdgcn_mfma_f32_32x32x16_bf16(a, b0, acc0, 0,0,0);
      acc1 = __builtin_amdgcn_mfma_f32_32x32x16_bf16(a, b1, acc1, 0,0,0);
      acc2 = __builtin_amdgcn_mfma_f32_32x32x16_bf16(a, b2, acc2, 0,0,0);
    }
    __builtin_amdgcn_sched_barrier(0);
    __builtin_amdgcn_s_barrier();          // all waves done reading buf
    if (s<5) stage(s+3);                   // refill buf (s+3)%3 == s%3
  }
  __syncthreads();                         // full drain before LDS reuse

  // ---- cross-K-slice reduction through LDS (aliases staging buffers) ----
  float* red = (float*)smem;                     // [r2][lane64][48]
  if (q==1) {
    const int base = (r*64+lane)*48;
    #pragma unroll
    for (int e=0;e<16;++e){ red[base+e]=acc0[e]; red[base+16+e]=acc1[e]; red[base+32+e]=acc2[e]; }
  }
  __syncthreads();
  if (q==1) return;
  {
    const int base = (r*64+lane)*48;
    #pragma unroll
    for (int e=0;e<16;++e){ acc0[e]+=red[base+e]; acc1[e]+=red[base+16+e]; acc2[e]+=red[base+32+e]; }
  }

  const int j = j0 + jl;
  const size_t TI = (size_t)(bid*2 + r);        // thread-row base for permuted buffers

  if (INIT) {
    float* gi = (float*)(ws+OFF_GI);
    const float* bih = d ? bihb : bihf;
    const float br = bih[j], bz = bih[1024+j], bn = bih[2048+j];
    #pragma unroll
    for (int qq=0;qq<16;++qq) {
      gi[(TI*48 + qq*3+0)*64 + lane] = acc0[qq] + br;
      gi[(TI*48 + qq*3+1)*64 + lane] = acc1[qq] + bz;
      gi[(TI*48 + qq*3+2)*64 + lane] = acc2[qq] + bn;
    }
  } else {
    const float* gi  = (const float*)(ws+OFF_GI);
    const float* bhh = d ? bhhb : bhhf;
    const float* h32p = (const float*)(ws+OFF_H32) + (size_t)p*524288;
    float*          h32n = (float*)(ws+OFF_H32) + (size_t)(p^1)*524288;
    __hip_bfloat16* h16n = (__hip_bfloat16*)(ws+OFF_H16) + (size_t)((p^1)*2+d)*NB*HD;
    float* part = (float*)(ws+OFF_PART);
    const float br = bhh[j], bz = bhh[1024+j], bn = bhh[2048+j];
    const float wo = wout[d*HD + j];
    #pragma unroll
    for (int qq=0;qq<16;++qq) {
      int brow = (qq&3) + 8*(qq>>2) + 4*(lane>>5);
      int b = r0 + r*32 + brow;
      float gir = gi[(TI*48 + qq*3+0)*64 + lane];
      float giz = gi[(TI*48 + qq*3+1)*64 + lane];
      float gin = gi[(TI*48 + qq*3+2)*64 + lane];
      float rr  = 1.f/(1.f + __expf(-(gir + acc0[qq] + br)));
      float zz  = 1.f/(1.f + __expf(-(giz + acc1[qq] + bz)));
      float ghn = acc2[qq] + bn;
      float ng  = tanhf(gin + rr*ghn);
      float hold = h32p[(TI*16 + qq)*64 + lane];
      float hn = (1.f - zz)*ng + zz*hold;
      h32n[(TI*16 + qq)*64 + lane] = hn;
      h16n[(size_t)b*HD + j] = __float2bfloat16(hn);
      float pp = hn * wo;                      // partial of out[b,t]
      #pragma unroll
      for (int m=1;m<32;m<<=1) pp += __shfl_xor(pp, m, 64);
      if (jl==0) part[((size_t)b*NT + t)*64 + d*32 + ct] = pp;
    }
  }
  #undef ABASE
  #undef BBASE
}

// ---------------- finalize: one wave per (b,t) output, f32 OUTPUT ----------------
__global__ __launch_bounds__(256) void finalize_kernel(
    const char* __restrict__ ws, const float* __restrict__ bout,
    float* __restrict__ out)
{
  int widx = blockIdx.x*4 + (threadIdx.x>>6);   // output index b*128+t, 32768 total
  int lane = threadIdx.x & 63;
  const float* part = (const float*)(ws+OFF_PART);
  float v = part[(size_t)widx*64 + lane];
  #pragma unroll
  for (int m=1;m<64;m<<=1) v += __shfl_xor(v, m, 64);
  if (lane==0) out[widx] = v + bout[0];
}

// ---------------- launch ----------------
extern "C" void kernel_launch(void* const* d_in, const int* in_sizes, int n_in,
                              void* d_out, int out_size, void* d_ws, size_t ws_size,
                              hipStream_t stream)
{
  const float* x    = (const float*)d_in[0];
  // d_in[1] = n (always 128 for this problem)
  const float* wihf = (const float*)d_in[2];
  const float* whhf = (const float*)d_in[3];
  const float* bihf = (const float*)d_in[4];
  const float* bhhf = (const float*)d_in[5];
  const float* wihb = (const float*)d_in[6];
  const float* whhb = (const float*)d_in[7];
  const float* bihb = (const float*)d_in[8];
  const float* bhhb = (const float*)d_in[9];
  const float* wout = (const float*)d_in[10];
  const float* bout = (const float*)d_in[11];
  char* ws = (char*)d_ws;
  float* out = (float*)d_out;

  prep_kernel<<<12288, 256, 0, stream>>>(x, wihf, whhf, wihb, whhb, ws);
  gru_gemm<1><<<256, 256, 0, stream>>>(ws, bihf, bihb, bhhf, bhhb, wout, 0);
  for (int t=0; t<NT; ++t)
    gru_gemm<0><<<256, 256, 0, stream>>>(ws, bihf, bihb, bhhf, bhhb, wout, t);
  finalize_kernel<<<8192, 256, 0, stream>>>(ws, bout, out);
}